// Round 1
// baseline (996.164 us; speedup 1.0000x reference)
//
#include <hip/hip_runtime.h>
#include <stdint.h>

// Problem constants
#define Bsz 32
#define TKs 2048
#define Nf  1024
#define Msz (Bsz*TKs)   // 65536 = rows of the fused GEMM
#define KTOT 2048       // h (1024) concat q_h (1024)

typedef __bf16 bf16x8 __attribute__((ext_vector_type(8)));
typedef float  f32x4  __attribute__((ext_vector_type(4)));
typedef float  f32x16 __attribute__((ext_vector_type(16)));

// round-half-up fp32->bf16, two at a time, packed into one u32
__device__ __forceinline__ unsigned pack_bf2(float f0, float f1){
  unsigned u0 = __float_as_uint(f0) + 0x8000u;
  unsigned u1 = __float_as_uint(f1) + 0x8000u;
  return __builtin_amdgcn_perm(u1, u0, 0x07060302u);
}

// tanh without clamps: e=inf -> 1, e=0 -> -1 (graceful); v_rcp_f32 ~1ulp
__device__ __forceinline__ float fast_tanh(float x){
  float e = __expf(2.f * x);
  return 1.f - 2.f * __builtin_amdgcn_rcpf(e + 1.f);
}

// async global->LDS, 16B per lane. LDS dest = wave-uniform base + lane*16.
__device__ __forceinline__ void async16(void* lds, const void* g){
  __builtin_amdgcn_global_load_lds(
      (const __attribute__((address_space(1))) unsigned int*)g,
      (__attribute__((address_space(3))) unsigned int*)lds,
      16, 0, 0);
}

// ---------------------------------------------------------------------------
// Kernel 1: pack W_h||W_q (fp32 [1024][1024] each) -> Wcat bf16 [1024][2048]
// ---------------------------------------------------------------------------
__global__ __launch_bounds__(256) void pack_w_kernel(
    const float* __restrict__ Wh, const float* __restrict__ Wq,
    unsigned short* __restrict__ Wcat)
{
  int idx = (blockIdx.x * 256 + threadIdx.x) * 4;
  int m = idx >> 11;
  int k = idx & 2047;
  const float* src = (k < 1024) ? (Wh + m * 1024 + k) : (Wq + m * 1024 + (k - 1024));
  float4 v = *(const float4*)src;
  uint2 p;
  p.x = pack_bf2(v.x, v.y);
  p.y = pack_bf2(v.z, v.w);
  *(uint2*)(Wcat + idx) = p;
}

// ---------------------------------------------------------------------------
// Kernel 2: dec_feat[b][m] = dot(s_t_hat[b], W_d[m]) + b_d[m]   (fp32, exact)
// ---------------------------------------------------------------------------
__global__ __launch_bounds__(256) void dec_kernel(
    const float* __restrict__ s_t, const float* __restrict__ Wd,
    const float* __restrict__ bd, float* __restrict__ dec)
{
  __shared__ float sv[1024];
  const int b = blockIdx.y;
  const int mbase = blockIdx.x * 64;
  for (int i = threadIdx.x; i < 1024; i += 256) sv[i] = s_t[b * 1024 + i];
  __syncthreads();
  const int wave = threadIdx.x >> 6, lane = threadIdx.x & 63;
  #pragma unroll 4
  for (int i = 0; i < 16; ++i){
    int m = mbase + wave * 16 + i;
    const float4* wr = (const float4*)(Wd + (size_t)m * 1024 + lane * 16);
    const float4* sr = (const float4*)(sv + lane * 16);
    float s = 0.f;
    #pragma unroll
    for (int j = 0; j < 4; ++j){
      float4 w = wr[j], x = sr[j];
      s += w.x * x.x + w.y * x.y + w.z * x.z + w.w * x.w;
    }
    #pragma unroll
    for (int d = 1; d < 64; d <<= 1) s += __shfl_xor(s, d);
    if (lane == 0) dec[b * 1024 + m] = s + bd[m];
  }
}

// ---------------------------------------------------------------------------
// Kernel 3: 32x32x16-MFMA GEMM + tanh + v-dot epilogue, with FUSED fp32->bf16
// A-staging (pack_a eliminated).
// 128x128 tile, BK=32. B: global_load_lds width-16 from pre-packed Wcat.
// A: fp32 h/q -> registers (prefetched during previous tile's MFMA phase) ->
//    pack_bf2 -> ds_write_b128 into the SAME XOR-swizzled layout:
//      k-group g of row r lives at LDS slot-pos g ^ ((r>>1)&3).
// Wave (wm,wn) computes 64x64 = 2x2 tiles of 32x32, 8 MFMA / kt.
// ---------------------------------------------------------------------------
__global__ __launch_bounds__(256) void gemm_fused_fast(
    const float* __restrict__ h, const float* __restrict__ q,
    const unsigned short* __restrict__ Wcat,
    const float* __restrict__ dec, const float* __restrict__ cov,
    const float* __restrict__ Wc, const float* __restrict__ vw,
    float* __restrict__ scoresP)
{
  __shared__ __align__(16) unsigned short As[128 * 32];
  __shared__ __align__(16) unsigned short Bs[128 * 32];
  __shared__ float ssum[2][128];
  __shared__ float covS[128];

  const int tid  = threadIdx.x;
  const int wave = tid >> 6, lane = tid & 63;
  const int wm = wave & 1, wn = wave >> 1;
  const int l31 = lane & 31, half = lane >> 5;

  const int p = blockIdx.x;
  const int ntile = (p >> 3) & 7;
  const int mtile = (p & 7) + ((p >> 6) << 3);
  const size_t growbase = (size_t)mtile * 128;

  if (tid < 128) covS[tid] = cov[growbase + tid];

  f32x16 acc[2][2];
  #pragma unroll
  for (int i = 0; i < 2; ++i)
    #pragma unroll
    for (int j = 0; j < 2; ++j)
      #pragma unroll
      for (int r = 0; r < 16; ++r) acc[i][j][r] = 0.f;

  // ---- staging geometry: 512 slots of 16B per tile; this thread owns s0,s1 ----
  const int s0 = wave * 128 + lane;          // 16B slots
  const int s1 = s0 + 64;
  const int r0 = s0 >> 2, g0 = (s0 & 3) ^ ((r0 >> 1) & 3);
  const int r1 = s1 >> 2, g1 = (s1 & 3) ^ ((r1 >> 1) & 3);

  // A: fp32 source offsets (row*1024 + swizzled-group*8); col base added per kt
  const size_t aOff0 = (size_t)(mtile * 128 + r0) * 1024 + g0 * 8;
  const size_t aOff1 = (size_t)(mtile * 128 + r1) * 1024 + g1 * 8;
  unsigned short* stA0 = &As[s0 * 8];
  unsigned short* stA1 = &As[s1 * 8];

  // B: bf16 source, global_load_lds (wave-uniform LDS base + lane*16)
  const unsigned short* pB0 = Wcat + (size_t)(ntile * 128 + r0) * 2048 + g0 * 8;
  const unsigned short* pB1 = Wcat + (size_t)(ntile * 128 + r1) * 2048 + g1 * 8;
  unsigned short* ldsB0 = &Bs[wave * 1024];
  unsigned short* ldsB1 = &Bs[wave * 1024 + 512];

  // ---- K-invariant fragment read pointers (swizzled) ----
  const bf16x8* a_rd[2][2];
  const bf16x8* b_rd[2][2];
  #pragma unroll
  for (int mi = 0; mi < 2; ++mi)
    #pragma unroll
    for (int ks = 0; ks < 2; ++ks){
      int row = wm * 64 + mi * 32 + l31;
      int g = ks * 2 + half;
      int pos = g ^ ((row >> 1) & 3);
      a_rd[mi][ks] = (const bf16x8*)&As[row * 32 + pos * 8];
    }
  #pragma unroll
  for (int ni = 0; ni < 2; ++ni)
    #pragma unroll
    for (int ks = 0; ks < 2; ++ks){
      int row = wn * 64 + ni * 32 + l31;
      int g = ks * 2 + half;
      int pos = g ^ ((row >> 1) & 3);
      b_rd[ni][ks] = (const bf16x8*)&Bs[row * 32 + pos * 8];
    }

  // ---- prologue: prefetch A for kt=0 (col 0, source h) ----
  float4 pf00 = *(const float4*)(h + aOff0);
  float4 pf01 = *(const float4*)(h + aOff0 + 4);
  float4 pf10 = *(const float4*)(h + aOff1);
  float4 pf11 = *(const float4*)(h + aOff1 + 4);

  for (int kt = 0; kt < KTOT / 32; ++kt){
    // pack prefetched A and store to swizzled LDS slots
    uint4 w0, w1;
    w0.x = pack_bf2(pf00.x, pf00.y); w0.y = pack_bf2(pf00.z, pf00.w);
    w0.z = pack_bf2(pf01.x, pf01.y); w0.w = pack_bf2(pf01.z, pf01.w);
    w1.x = pack_bf2(pf10.x, pf10.y); w1.y = pack_bf2(pf10.z, pf10.w);
    w1.z = pack_bf2(pf11.x, pf11.y); w1.w = pack_bf2(pf11.z, pf11.w);
    *(uint4*)stA0 = w0;
    *(uint4*)stA1 = w1;
    // B tile async global->LDS
    async16(ldsB0, pB0);
    async16(ldsB1, pB1);
    pB0 += 32; pB1 += 32;
    __syncthreads();

    // issue A prefetch for next tile early: hides HBM latency under MFMA,
    // drained by the compiler's vmcnt(0) at the END barrier, not this one.
    if (kt < KTOT / 32 - 1){
      int c = ((kt + 1) * 32) & 1023;
      const float* sp = (kt + 1 < 32) ? h : q;
      pf00 = *(const float4*)(sp + aOff0 + c);
      pf01 = *(const float4*)(sp + aOff0 + c + 4);
      pf10 = *(const float4*)(sp + aOff1 + c);
      pf11 = *(const float4*)(sp + aOff1 + c + 4);
    }

    bf16x8 af[2][2], bg[2][2];
    #pragma unroll
    for (int i = 0; i < 2; ++i)
      #pragma unroll
      for (int ks = 0; ks < 2; ++ks){ af[i][ks] = *a_rd[i][ks]; bg[i][ks] = *b_rd[i][ks]; }
    #pragma unroll
    for (int ks = 0; ks < 2; ++ks)
      #pragma unroll
      for (int mi = 0; mi < 2; ++mi)
        #pragma unroll
        for (int ni = 0; ni < 2; ++ni)
          acc[mi][ni] = __builtin_amdgcn_mfma_f32_32x32x16_bf16(
              af[mi][ks], bg[ni][ks], acc[mi][ni], 0, 0, 0);
    __syncthreads();
  }

  // ---- epilogue: tanh + v-dot; C/D: col=lane&31, row=(r&3)+8*(r>>2)+4*half ----
  const int brow = (mtile * 128) >> 11;
  const float* decb = dec + brow * 1024;
  float dv[2], wc2[2], vw2[2];
  #pragma unroll
  for (int ni = 0; ni < 2; ++ni){
    int col = ntile * 128 + wn * 64 + ni * 32 + l31;
    dv[ni]  = decb[col];
    wc2[ni] = Wc[col];
    vw2[ni] = vw[col];
  }
  #pragma unroll
  for (int mi = 0; mi < 2; ++mi){
    #pragma unroll
    for (int r = 0; r < 16; ++r){
      int rl = wm * 64 + mi * 32 + (r & 3) + 8 * (r >> 2) + 4 * half;
      float cv = covS[rl];
      float s = 0.f;
      #pragma unroll
      for (int ni = 0; ni < 2; ++ni){
        float x = acc[mi][ni][r] + dv[ni] + cv * wc2[ni];
        s += vw2[ni] * fast_tanh(x);
      }
      #pragma unroll
      for (int d = 1; d < 32; d <<= 1) s += __shfl_xor(s, d);  // within 32-lane half
      if (l31 == 0) ssum[wn][rl] = s;
    }
  }
  __syncthreads();
  if (tid < 128)
    scoresP[(size_t)ntile * Msz + growbase + tid] = ssum[0][tid] + ssum[1][tid];
}

// ---------------------------------------------------------------------------
// Kernel 4: masked renormalized softmax (softmax denom cancels) + coverage_out
// ---------------------------------------------------------------------------
__global__ __launch_bounds__(256) void softmax_kernel(
    const float* __restrict__ scoresP, const float* __restrict__ mask,
    const float* __restrict__ cov, float* __restrict__ attn_o,
    float* __restrict__ cov_o)
{
  const int b = blockIdx.x;
  const int tid = threadIdx.x;
  const int wave = tid >> 6, lane = tid & 63;
  __shared__ float redm[4], reds[4];
  float sc[8];
  float mx = -3.4e38f;
  #pragma unroll
  for (int j = 0; j < 8; ++j){
    int t = tid + j * 256;
    float s = 0.f;
    #pragma unroll
    for (int p = 0; p < 8; ++p) s += scoresP[(size_t)p * Msz + b * TKs + t];
    sc[j] = s;
    mx = fmaxf(mx, s);
  }
  #pragma unroll
  for (int d = 1; d < 64; d <<= 1) mx = fmaxf(mx, __shfl_xor(mx, d));
  if (lane == 0) redm[wave] = mx;
  __syncthreads();
  mx = fmaxf(fmaxf(redm[0], redm[1]), fmaxf(redm[2], redm[3]));
  float e[8]; float sum = 0.f;
  #pragma unroll
  for (int j = 0; j < 8; ++j){
    int t = tid + j * 256;
    float v = __expf(sc[j] - mx) * mask[b * TKs + t];
    e[j] = v; sum += v;
  }
  #pragma unroll
  for (int d = 1; d < 64; d <<= 1) sum += __shfl_xor(sum, d);
  if (lane == 0) reds[wave] = sum;
  __syncthreads();
  sum = reds[0] + reds[1] + reds[2] + reds[3];
  float inv = 1.f / sum;
  #pragma unroll
  for (int j = 0; j < 8; ++j){
    int t = tid + j * 256;
    float a = e[j] * inv;
    attn_o[b * TKs + t] = a;
    cov_o[b * TKs + t]  = cov[b * TKs + t] + a;
  }
}

// ---------------------------------------------------------------------------
// Kernel 5: c_t partials (fp32 h, proven path) + reduce
// ---------------------------------------------------------------------------
__global__ __launch_bounds__(256) void ct_partial(
    const float* __restrict__ h, const float* __restrict__ attn,
    float* __restrict__ P)
{
  const int b = blockIdx.y, tc = blockIdx.x;
  const int n4 = threadIdx.x * 4;
  float4 acc = {0.f, 0.f, 0.f, 0.f};
  const float* hb = h + ((size_t)b * TKs + tc * 64) * Nf;
  const float* ab = attn + b * TKs + tc * 64;
  #pragma unroll 4
  for (int tt = 0; tt < 64; ++tt){
    float a = ab[tt];
    float4 hv = *(const float4*)(hb + (size_t)tt * Nf + n4);
    acc.x += a * hv.x; acc.y += a * hv.y; acc.z += a * hv.z; acc.w += a * hv.w;
  }
  *(float4*)(P + ((size_t)(tc * Bsz + b)) * Nf + n4) = acc;
}

__global__ __launch_bounds__(256) void ct_reduce(
    const float* __restrict__ P, float* __restrict__ out)
{
  int bn = (blockIdx.x * 256 + threadIdx.x) * 4;
  float4 s = {0.f, 0.f, 0.f, 0.f};
  for (int j = 0; j < 32; ++j){
    float4 v = *(const float4*)(P + (size_t)j * (Bsz * Nf) + bn);
    s.x += v.x; s.y += v.y; s.z += v.z; s.w += v.w;
  }
  *(float4*)(out + bn) = s;
}

// ---------------------------------------------------------------------------
extern "C" void kernel_launch(void* const* d_in, const int* in_sizes, int n_in,
                              void* d_out, int out_size, void* d_ws, size_t ws_size,
                              hipStream_t stream) {
  const float* s_t  = (const float*)d_in[0];
  const float* h    = (const float*)d_in[1];
  const float* mask = (const float*)d_in[2];
  const float* cov  = (const float*)d_in[3];
  const float* qh   = (const float*)d_in[4];
  const float* Wh   = (const float*)d_in[5];
  const float* Wq   = (const float*)d_in[6];
  const float* Wc   = (const float*)d_in[7];
  const float* Wd   = (const float*)d_in[8];
  const float* bd   = (const float*)d_in[9];
  const float* vw   = (const float*)d_in[10];

  float* out    = (float*)d_out;
  float* c_t    = out;                 // [32,1024]
  float* attn_o = out + Bsz * Nf;      // [32,2048]
  float* cov_o  = attn_o + Bsz * TKs;  // [32,2048]

  char* ws = (char*)d_ws;
  unsigned short* Wcat = (unsigned short*)ws;                      // 4 MB
  float* dec     = (float*)(ws + (4u << 20));                      // 128 KB
  float* scoresP = (float*)(ws + (4u << 20) + (128u << 10));       // 2 MB
  float* ctP     = (float*)(ws + (6u << 20) + (128u << 10));       // 4 MB

  hipLaunchKernelGGL(pack_w_kernel, dim3(2048), dim3(256), 0, stream, Wh, Wq, Wcat);
  hipLaunchKernelGGL(dec_kernel,    dim3(16, 32), dim3(256), 0, stream, s_t, Wd, bd, dec);
  hipLaunchKernelGGL(gemm_fused_fast, dim3(4096), dim3(256), 0, stream,
                     h, qh, Wcat, dec, cov, Wc, vw, scoresP);
  hipLaunchKernelGGL(softmax_kernel, dim3(32), dim3(256), 0, stream,
                     scoresP, mask, cov, attn_o, cov_o);
  hipLaunchKernelGGL(ct_partial, dim3(32, 32), dim3(256), 0, stream, h, attn_o, ctP);
  hipLaunchKernelGGL(ct_reduce,  dim3(32), dim3(256), 0, stream, ctP, c_t);
}

// Round 2
// 937.584 us; speedup vs baseline: 1.0625x; 1.0625x over previous
//
#include <hip/hip_runtime.h>
#include <stdint.h>

// Problem constants
#define Bsz 32
#define TKs 2048
#define Nf  1024
#define Msz (Bsz*TKs)   // 65536 = rows of the fused GEMM
#define KTOT 2048       // h (1024) concat q_h (1024)

typedef __bf16 bf16x8 __attribute__((ext_vector_type(8)));
typedef float  f32x16 __attribute__((ext_vector_type(16)));

// round-half-up fp32->bf16, two at a time, packed into one u32
__device__ __forceinline__ unsigned pack_bf2(float f0, float f1){
  unsigned u0 = __float_as_uint(f0) + 0x8000u;
  unsigned u1 = __float_as_uint(f1) + 0x8000u;
  return __builtin_amdgcn_perm(u1, u0, 0x07060302u);
}

// tanh without clamps: e=inf -> 1, e=0 -> -1 (graceful); v_rcp_f32 ~1ulp
__device__ __forceinline__ float fast_tanh(float x){
  float e = __expf(2.f * x);
  return 1.f - 2.f * __builtin_amdgcn_rcpf(e + 1.f);
}

// async global->LDS, 16B per lane. LDS dest = wave-uniform base + lane*16;
// global source address is PER-LANE (this is how the swizzle is applied).
__device__ __forceinline__ void async16(void* lds, const void* g){
  __builtin_amdgcn_global_load_lds(
      (const __attribute__((address_space(1))) unsigned int*)g,
      (__attribute__((address_space(3))) unsigned int*)lds,
      16, 0, 0);
}

// ---------------------------------------------------------------------------
// Kernel 1: pack W_h||W_q (fp32 [1024][1024] each) -> Wcat bf16 [1024][2048]
// ---------------------------------------------------------------------------
__global__ __launch_bounds__(256) void pack_w_kernel(
    const float* __restrict__ Wh, const float* __restrict__ Wq,
    unsigned short* __restrict__ Wcat)
{
  int idx = (blockIdx.x * 256 + threadIdx.x) * 4;
  int m = idx >> 11;
  int k = idx & 2047;
  const float* src = (k < 1024) ? (Wh + m * 1024 + k) : (Wq + m * 1024 + (k - 1024));
  float4 v = *(const float4*)src;
  uint2 p;
  p.x = pack_bf2(v.x, v.y);
  p.y = pack_bf2(v.z, v.w);
  *(uint2*)(Wcat + idx) = p;
}

// ---------------------------------------------------------------------------
// Kernel 1b: pack A = h||q (fp32) -> Acat bf16 [65536][2048]
// (256 MB bf16 fits L3 -> GEMM's 4x ntile re-reads of A are absorbed.)
// ---------------------------------------------------------------------------
__global__ __launch_bounds__(256) void pack_a_kernel(
    const float* __restrict__ h, const float* __restrict__ q,
    unsigned short* __restrict__ Acat)
{
  size_t idx = ((size_t)blockIdx.x * 256 + threadIdx.x) * 8;
  size_t r = idx >> 11;
  int c = (int)(idx & 2047);
  const float* src = (c < 1024) ? (h + r * 1024 + c) : (q + r * 1024 + (c - 1024));
  float4 v0 = ((const float4*)src)[0];
  float4 v1 = ((const float4*)src)[1];
  uint4 p;
  p.x = pack_bf2(v0.x, v0.y); p.y = pack_bf2(v0.z, v0.w);
  p.z = pack_bf2(v1.x, v1.y); p.w = pack_bf2(v1.z, v1.w);
  *(uint4*)(Acat + idx) = p;
}

// ---------------------------------------------------------------------------
// Kernel 2: dec_feat[b][m] = dot(s_t_hat[b], W_d[m]) + b_d[m]   (fp32, exact)
// ---------------------------------------------------------------------------
__global__ __launch_bounds__(256) void dec_kernel(
    const float* __restrict__ s_t, const float* __restrict__ Wd,
    const float* __restrict__ bd, float* __restrict__ dec)
{
  __shared__ float sv[1024];
  const int b = blockIdx.y;
  const int mbase = blockIdx.x * 64;
  for (int i = threadIdx.x; i < 1024; i += 256) sv[i] = s_t[b * 1024 + i];
  __syncthreads();
  const int wave = threadIdx.x >> 6, lane = threadIdx.x & 63;
  #pragma unroll 4
  for (int i = 0; i < 16; ++i){
    int m = mbase + wave * 16 + i;
    const float4* wr = (const float4*)(Wd + (size_t)m * 1024 + lane * 16);
    const float4* sr = (const float4*)(sv + lane * 16);
    float s = 0.f;
    #pragma unroll
    for (int j = 0; j < 4; ++j){
      float4 w = wr[j], x = sr[j];
      s += w.x * x.x + w.y * x.y + w.z * x.z + w.w * x.w;
    }
    #pragma unroll
    for (int d = 1; d < 64; d <<= 1) s += __shfl_xor(s, d);
    if (lane == 0) dec[b * 1024 + m] = s + bd[m];
  }
}

// ---------------------------------------------------------------------------
// Kernel 3: 256x256-tile deep-pipelined MFMA GEMM + tanh + v-dot epilogue.
//   512 threads = 8 waves (2 M x 4 N), per-wave output 128x64.
//   BK=64, double-buffered LDS: As/Bs = 2 x [256 rows][64 K] bf16 = 128 KB.
//   Staging: global_load_lds w16, LINEAR LDS dest; swizzle kg' = kg ^ (row&7)
//   applied on the per-lane GLOBAL source, inverse applied on ds_read addrs.
//   Pipeline per K-step: {reads ks01 -> MFMA x16} {reads ks23 -> lgkm0 ->
//   barrier -> stage kt+2 -> MFMA x16 -> vmcnt(8) -> barrier}.  vmcnt never
//   drains to 0 in the main loop (T3+T4); setprio(1) around MFMA (T5).
// ---------------------------------------------------------------------------
__global__ __launch_bounds__(512, 2) void gemm_fused_fast(
    const unsigned short* __restrict__ Acat,
    const unsigned short* __restrict__ Wcat,
    const float* __restrict__ dec, const float* __restrict__ cov,
    const float* __restrict__ Wc, const float* __restrict__ vw,
    float* __restrict__ scoresP)
{
  __shared__ __align__(16) unsigned short As[2 * 256 * 64];   // 64 KB
  __shared__ __align__(16) unsigned short Bs[2 * 256 * 64];   // 64 KB

  const int tid  = threadIdx.x;
  const int l    = tid & 63, w = tid >> 6;        // lane, wave 0..7
  const int wm   = w & 1, wn = w >> 1;            // 2 x 4 wave grid
  const int l31  = l & 31, half = l >> 5;

  // XCD-chunked swizzle: XCD x runs a contiguous orig range -> A-panel (1MB)
  // reused 4x (ntiles) inside one XCD's L2; B panel L2-resident.
  const int bid   = blockIdx.x;                   // 1024 blocks, %8==0
  const int orig  = (bid & 7) * 128 + (bid >> 3);
  const int mtile = orig >> 2;                    // 0..255
  const int ntile = orig & 3;                     // 0..3

  f32x16 acc[4][2];
  #pragma unroll
  for (int mi = 0; mi < 4; ++mi)
    #pragma unroll
    for (int ni = 0; ni < 2; ++ni)
      #pragma unroll
      for (int r = 0; r < 16; ++r) acc[mi][ni][r] = 0.f;

  // ---- staging source (per-lane, pre-swizzled) ----
  // slot s = j*512 + tid  ->  row = s>>3 = j*64 + (tid>>3),  kg' = s&7 = tid&7,
  // source kg = kg' ^ (row&7) = (tid&7) ^ ((tid>>3)&7)   (j-invariant).
  const int t8  = tid >> 3;
  const int kgS = (tid & 7) ^ (t8 & 7);
  const unsigned short* aS = Acat + (size_t)(mtile * 256 + t8) * 2048 + kgS * 8;
  const unsigned short* bS = Wcat + (size_t)(ntile * 256 + t8) * 2048 + kgS * 8;

#define STAGE(bsel, kt_) do {                                                   \
    _Pragma("unroll")                                                           \
    for (int j = 0; j < 4; ++j) {                                               \
      async16(&As[(bsel) * 16384 + j * 4096 + w * 512],                         \
              aS + (size_t)(kt_) * 64 + (size_t)j * 131072);                    \
      async16(&Bs[(bsel) * 16384 + j * 4096 + w * 512],                         \
              bS + (size_t)(kt_) * 64 + (size_t)j * 131072);                    \
    }                                                                           \
  } while (0)

  // ---- fragment read indices (swizzled): elem (row, kg) at row*64 + kg'*8,
  //      kg' = kg ^ (row&7); row&7 == l&7 for all our fragment rows. ----
  const int aRow = (wm * 128 + l31) * 64;
  const int bRow = (wn * 64  + l31) * 64;
  int kgx[4];
  #pragma unroll
  for (int ks = 0; ks < 4; ++ks) kgx[ks] = (((ks * 2 + half) ^ (l & 7))) * 8;

  // ---- prologue: stage kt0 -> buf0, kt1 -> buf1; wait only for kt0 ----
  STAGE(0, 0);
  STAGE(1, 1);
  asm volatile("s_waitcnt vmcnt(8)" ::: "memory");
  __builtin_amdgcn_s_barrier();

  for (int kt = 0; kt < 32; ++kt){
    const int bo = (kt & 1) * 16384;
    // ---------- phase 1: ks = 0,1 ----------
    bf16x8 aF[4][2], bF[2][2];
    #pragma unroll
    for (int mi = 0; mi < 4; ++mi)
      #pragma unroll
      for (int ks = 0; ks < 2; ++ks)
        aF[mi][ks] = *(const bf16x8*)&As[bo + aRow + mi * 2048 + kgx[ks]];
    #pragma unroll
    for (int ni = 0; ni < 2; ++ni)
      #pragma unroll
      for (int ks = 0; ks < 2; ++ks)
        bF[ni][ks] = *(const bf16x8*)&Bs[bo + bRow + ni * 2048 + kgx[ks]];
    __builtin_amdgcn_s_setprio(1);
    #pragma unroll
    for (int ks = 0; ks < 2; ++ks)
      #pragma unroll
      for (int mi = 0; mi < 4; ++mi)
        #pragma unroll
        for (int ni = 0; ni < 2; ++ni)
          acc[mi][ni] = __builtin_amdgcn_mfma_f32_32x32x16_bf16(
              aF[mi][ks], bF[ni][ks], acc[mi][ni], 0, 0, 0);
    __builtin_amdgcn_s_setprio(0);
    // ---------- phase 2: ks = 2,3 ----------
    bf16x8 aG[4][2], bG[2][2];
    #pragma unroll
    for (int mi = 0; mi < 4; ++mi)
      #pragma unroll
      for (int ks = 0; ks < 2; ++ks)
        aG[mi][ks] = *(const bf16x8*)&As[bo + aRow + mi * 2048 + kgx[2 + ks]];
    #pragma unroll
    for (int ni = 0; ni < 2; ++ni)
      #pragma unroll
      for (int ks = 0; ks < 2; ++ks)
        bG[ni][ks] = *(const bf16x8*)&Bs[bo + bRow + ni * 2048 + kgx[2 + ks]];
    // all of THIS wave's reads of buf bo retired -> rendezvous -> overwrite ok
    asm volatile("s_waitcnt lgkmcnt(0)" ::: "memory");
    __builtin_amdgcn_sched_barrier(0);
    __builtin_amdgcn_s_barrier();
    __builtin_amdgcn_sched_barrier(0);
    if (kt < 30) STAGE(kt & 1, kt + 2);
    __builtin_amdgcn_s_setprio(1);
    #pragma unroll
    for (int ks = 0; ks < 2; ++ks)
      #pragma unroll
      for (int mi = 0; mi < 4; ++mi)
        #pragma unroll
        for (int ni = 0; ni < 2; ++ni)
          acc[mi][ni] = __builtin_amdgcn_mfma_f32_32x32x16_bf16(
              aG[mi][ks], bG[ni][ks], acc[mi][ni], 0, 0, 0);
    __builtin_amdgcn_s_setprio(0);
    // wait ONLY for next K-step's 8 loads (kt+2's 8 stay in flight)
    if (kt < 30) { asm volatile("s_waitcnt vmcnt(8)" ::: "memory"); }
    else         { asm volatile("s_waitcnt vmcnt(0)" ::: "memory"); }
    __builtin_amdgcn_s_barrier();
  }
#undef STAGE

  // ---- epilogue: tanh + v-dot; C/D: col=lane&31, row=(r&3)+8*(r>>2)+4*half ----
  float* ssum = (float*)As;                 // As dead; [4][256] partials
  const size_t growbase = (size_t)mtile * 256;
  const int brow = mtile >> 3;              // batch index (2048 rows / batch)
  const float* decb = dec + brow * 1024;
  float dv[2], wc2[2], vw2[2];
  #pragma unroll
  for (int ni = 0; ni < 2; ++ni){
    int col = ntile * 256 + wn * 64 + ni * 32 + l31;
    dv[ni]  = decb[col];
    wc2[ni] = Wc[col];
    vw2[ni] = vw[col];
  }
  #pragma unroll
  for (int mi = 0; mi < 4; ++mi){
    #pragma unroll
    for (int rq = 0; rq < 4; ++rq){
      const int rbase = wm * 128 + mi * 32 + 8 * rq + 4 * half;
      float4 cvv = *(const float4*)&cov[growbase + rbase];
      #pragma unroll
      for (int rb = 0; rb < 4; ++rb){
        const int r = rq * 4 + rb;
        float cv = (&cvv.x)[rb];
        float s = 0.f;
        #pragma unroll
        for (int ni = 0; ni < 2; ++ni){
          float x = acc[mi][ni][r] + dv[ni] + cv * wc2[ni];
          s += vw2[ni] * fast_tanh(x);
        }
        #pragma unroll
        for (int d = 1; d < 32; d <<= 1) s += __shfl_xor(s, d);
        if (l31 == 0) ssum[wn * 256 + rbase + rb] = s;
      }
    }
  }
  asm volatile("s_waitcnt lgkmcnt(0)" ::: "memory");
  __builtin_amdgcn_s_barrier();
  if (tid < 256)
    scoresP[(size_t)ntile * Msz + growbase + tid] =
        ssum[tid] + ssum[256 + tid] + ssum[512 + tid] + ssum[768 + tid];
}

// ---------------------------------------------------------------------------
// Kernel 4: masked renormalized softmax (denom cancels) + coverage_out
// ---------------------------------------------------------------------------
__global__ __launch_bounds__(256) void softmax_kernel(
    const float* __restrict__ scoresP, const float* __restrict__ mask,
    const float* __restrict__ cov, float* __restrict__ attn_o,
    float* __restrict__ cov_o)
{
  const int b = blockIdx.x;
  const int tid = threadIdx.x;
  const int wave = tid >> 6, lane = tid & 63;
  __shared__ float redm[4], reds[4];
  float sc[8];
  float mx = -3.4e38f;
  #pragma unroll
  for (int j = 0; j < 8; ++j){
    int t = tid + j * 256;
    float s = 0.f;
    #pragma unroll
    for (int p = 0; p < 4; ++p) s += scoresP[(size_t)p * Msz + b * TKs + t];
    sc[j] = s;
    mx = fmaxf(mx, s);
  }
  #pragma unroll
  for (int d = 1; d < 64; d <<= 1) mx = fmaxf(mx, __shfl_xor(mx, d));
  if (lane == 0) redm[wave] = mx;
  __syncthreads();
  mx = fmaxf(fmaxf(redm[0], redm[1]), fmaxf(redm[2], redm[3]));
  float e[8]; float sum = 0.f;
  #pragma unroll
  for (int j = 0; j < 8; ++j){
    int t = tid + j * 256;
    float v = __expf(sc[j] - mx) * mask[b * TKs + t];
    e[j] = v; sum += v;
  }
  #pragma unroll
  for (int d = 1; d < 64; d <<= 1) sum += __shfl_xor(sum, d);
  if (lane == 0) reds[wave] = sum;
  __syncthreads();
  sum = reds[0] + reds[1] + reds[2] + reds[3];
  float inv = 1.f / sum;
  #pragma unroll
  for (int j = 0; j < 8; ++j){
    int t = tid + j * 256;
    float a = e[j] * inv;
    attn_o[b * TKs + t] = a;
    cov_o[b * TKs + t]  = cov[b * TKs + t] + a;
  }
}

// ---------------------------------------------------------------------------
// Kernel 5: c_t partials (bf16 h from Acat) + reduce
// ---------------------------------------------------------------------------
__global__ __launch_bounds__(256) void ct_partial_bf(
    const unsigned short* __restrict__ Acat, const float* __restrict__ attn,
    float* __restrict__ P)
{
  const int b = blockIdx.y, tc = blockIdx.x;
  const int c4 = threadIdx.x * 4;
  float4 acc = {0.f, 0.f, 0.f, 0.f};
  const size_t rbase = (size_t)b * TKs + tc * 64;
  const float* ab = attn + b * TKs + tc * 64;
  #pragma unroll 4
  for (int tt = 0; tt < 64; ++tt){
    float a = ab[tt];
    uint2 v = *(const uint2*)(Acat + (rbase + tt) * 2048 + c4);
    acc.x += a * __uint_as_float(v.x << 16);
    acc.y += a * __uint_as_float(v.x & 0xffff0000u);
    acc.z += a * __uint_as_float(v.y << 16);
    acc.w += a * __uint_as_float(v.y & 0xffff0000u);
  }
  *(float4*)(P + ((size_t)(tc * Bsz + b)) * Nf + c4) = acc;
}

__global__ __launch_bounds__(256) void ct_reduce(
    const float* __restrict__ P, float* __restrict__ out)
{
  int bn = (blockIdx.x * 256 + threadIdx.x) * 4;
  float4 s = {0.f, 0.f, 0.f, 0.f};
  for (int j = 0; j < 32; ++j){
    float4 v = *(const float4*)(P + (size_t)j * (Bsz * Nf) + bn);
    s.x += v.x; s.y += v.y; s.z += v.z; s.w += v.w;
  }
  *(float4*)(out + bn) = s;
}

// ---------------------------------------------------------------------------
extern "C" void kernel_launch(void* const* d_in, const int* in_sizes, int n_in,
                              void* d_out, int out_size, void* d_ws, size_t ws_size,
                              hipStream_t stream) {
  const float* s_t  = (const float*)d_in[0];
  const float* h    = (const float*)d_in[1];
  const float* mask = (const float*)d_in[2];
  const float* cov  = (const float*)d_in[3];
  const float* qh   = (const float*)d_in[4];
  const float* Wh   = (const float*)d_in[5];
  const float* Wq   = (const float*)d_in[6];
  const float* Wc   = (const float*)d_in[7];
  const float* Wd   = (const float*)d_in[8];
  const float* bd   = (const float*)d_in[9];
  const float* vw   = (const float*)d_in[10];

  float* out    = (float*)d_out;
  float* c_t    = out;                 // [32,1024]
  float* attn_o = out + Bsz * Nf;      // [32,2048]
  float* cov_o  = attn_o + Bsz * TKs;  // [32,2048]

  char* ws = (char*)d_ws;
  unsigned short* Wcat = (unsigned short*)ws;                      // 4 MB
  float* dec     = (float*)(ws + (4u << 20));                      // 128 KB
  float* scoresP = (float*)(ws + (4u << 20) + (128u << 10));       // 1 MB used
  float* ctP     = (float*)(ws + (6u << 20) + (128u << 10));       // 4 MB
  unsigned short* Acat = (unsigned short*)(ws + (16ull << 20));    // 268.4 MB

  hipLaunchKernelGGL(pack_w_kernel, dim3(2048), dim3(256), 0, stream, Wh, Wq, Wcat);
  hipLaunchKernelGGL(dec_kernel,    dim3(16, 32), dim3(256), 0, stream, s_t, Wd, bd, dec);
  hipLaunchKernelGGL(pack_a_kernel, dim3((unsigned)((size_t)Msz * KTOT / 8 / 256)),
                     dim3(256), 0, stream, h, qh, Acat);
  hipLaunchKernelGGL(gemm_fused_fast, dim3(1024), dim3(512), 0, stream,
                     Acat, Wcat, dec, cov, Wc, vw, scoresP);
  hipLaunchKernelGGL(softmax_kernel, dim3(32), dim3(256), 0, stream,
                     scoresP, mask, cov, attn_o, cov_o);
  hipLaunchKernelGGL(ct_partial_bf, dim3(32, 32), dim3(256), 0, stream, Acat, attn_o, ctP);
  hipLaunchKernelGGL(ct_reduce,  dim3(32), dim3(256), 0, stream, ctP, c_t);
}